// Round 4
// baseline (1368.682 us; speedup 1.0000x reference)
//
#include <hip/hip_runtime.h>

#define H 2048
#define W 2048
#define NIMG 4
#define HWPX (H*W)               // 4194304 = 2^22
#define K_RANK 2097151u          // (n-1)//2

__device__ __forceinline__ unsigned fmap(float f) {
    unsigned u = __float_as_uint(f);
    return (u & 0x80000000u) ? ~u : (u | 0x80000000u);
}

// ---------------- P0: convert f32 gaussian taps to f64 in ws
__global__ void k_prep(const float* __restrict__ gk, double* __restrict__ kwd) {
    int t = threadIdx.x;
    if (t < 49) kwd[t] = (double)gk[t];
}

// ---------------- P1: sobel -> f64 products staged in LDS -> direct 7x7 f64 conv -> R(f32)
// + fused 4096-bin histogram + fused (last-block) coarse scan
// tile 64w x 32h, 512 threads, each thread 2 cols x 2 rows
__global__ __launch_bounds__(512, 4) void k_harris_R(const float* __restrict__ x,
                                                     const double* __restrict__ kwd,
                                                     float* __restrict__ R,
                                                     unsigned* __restrict__ hist1,
                                                     unsigned* __restrict__ ticket1,
                                                     int* __restrict__ metaBin,
                                                     int* __restrict__ metaBase)
{
    __shared__ float xs[2880];                      // [40][72] f32, rows y0-4.., cols x0-4..
    __align__(16) __shared__ double prods[8208];    // 3 planes [38][72] f64 (cols 0..69 valid)
    __shared__ unsigned lastv;
    unsigned* hist = (unsigned*)prods;              // first 16KB of prods, used after conv
    unsigned* sc   = ((unsigned*)prods) + 4096;     // 512-entry scan area (bytes 16K..18K)

    const int tid = threadIdx.x;
    const int img = blockIdx.z;
    const int x0 = blockIdx.x * 64, y0 = blockIdx.y * 32;
    const float* __restrict__ X = x + (size_t)img * HWPX;

    // stage x tile with halo 4 (zero-padded)
    for (int i = tid; i < 2880; i += 512) {
        int r = i / 72, c = i - r * 72;
        int gy = y0 - 4 + r, gx = x0 - 4 + c;
        float v = 0.f;
        if ((unsigned)gy < H && (unsigned)gx < W) v = X[(size_t)gy * W + gx];
        xs[i] = v;
    }
    __syncthreads();

    // sobel (f64-exact from f32) + products, staged once per plane pixel
    for (int i = tid; i < 2736; i += 512) {        // 38*72
        int r = i / 72, c = i - r * 72;
        if (c < 70) {
            int gy = y0 - 3 + r, gx = x0 - 3 + c;
            double pxx = 0.0, pyy = 0.0, pxy = 0.0;
            if ((unsigned)gy < H && (unsigned)gx < W) {
                const float* p0 = &xs[r * 72 + c];
                double x00 = p0[0],   x01 = p0[1],   x02 = p0[2];
                double x10 = p0[72],                  x12 = p0[74];
                double x20 = p0[144], x21 = p0[145], x22 = p0[146];
                double ix = (x02 - x00) + 2.0 * (x12 - x10) + (x22 - x20);
                double iy = (x20 - x00) + 2.0 * (x21 - x01) + (x22 - x02);
                pxx = ix * ix; pyy = iy * iy; pxy = ix * iy;
            }
            prods[i] = pxx;
            prods[2736 + i] = pyy;
            prods[5472 + i] = pxy;
        }
    }
    __syncthreads();

    const int tc = (tid & 31) * 2;       // cols tc, tc+1 (0..62)
    const int tr = (tid >> 5) * 2;       // rows tr, tr+1 (0..30)

    double acc[3][2][2];
    #pragma unroll
    for (int ch = 0; ch < 3; ch++)
        #pragma unroll
        for (int rr = 0; rr < 2; rr++) { acc[ch][rr][0] = 0.0; acc[ch][rr][1] = 0.0; }

    #pragma unroll
    for (int ii = 0; ii < 8; ii++) {
        const int pr = tr + ii;
        #pragma unroll
        for (int ch = 0; ch < 3; ch++) {
            double pv[8];
            const double2* prow = (const double2*)&prods[ch * 2736 + pr * 72 + tc];
            #pragma unroll
            for (int q = 0; q < 4; q++) { double2 t = prow[q]; pv[2*q] = t.x; pv[2*q+1] = t.y; }
            if (ii <= 6) {
                #pragma unroll
                for (int j = 0; j < 7; j++) {
                    double w = kwd[ii * 7 + j];
                    acc[ch][0][0] = fma(w, pv[j],   acc[ch][0][0]);
                    acc[ch][0][1] = fma(w, pv[j+1], acc[ch][0][1]);
                }
            }
            if (ii >= 1) {
                #pragma unroll
                for (int j = 0; j < 7; j++) {
                    double w = kwd[(ii - 1) * 7 + j];
                    acc[ch][1][0] = fma(w, pv[j],   acc[ch][1][0]);
                    acc[ch][1][1] = fma(w, pv[j+1], acc[ch][1][1]);
                }
            }
        }
    }

    // R values + global store (keep fmap bins in regs for hist)
    float* __restrict__ Ri = R + (size_t)img * HWPX;
    unsigned bins[4];
    #pragma unroll
    for (int rr = 0; rr < 2; rr++) {
        float2 o;
        #pragma unroll
        for (int cc = 0; cc < 2; cc++) {
            double sxx = acc[0][rr][cc], syy = acc[1][rr][cc], sxy = acc[2][rr][cc];
            double t2 = sxx + syy;
            double Rv = sxx * syy - sxy * sxy - 0.05 * t2 * t2;
            ((float*)&o)[cc] = (float)Rv;
        }
        *(float2*)&Ri[(size_t)(y0 + tr + rr) * W + (x0 + tc)] = o;
        bins[rr * 2]     = fmap(o.x) >> 20;
        bins[rr * 2 + 1] = fmap(o.y) >> 20;
    }
    __syncthreads();                               // all conv reads of prods done

    for (int i = tid; i < 4096; i += 512) hist[i] = 0;
    __syncthreads();
    #pragma unroll
    for (int q = 0; q < 4; q++) atomicAdd(&hist[bins[q]], 1u);
    __syncthreads();

    unsigned* gh = hist1 + img * 4096;
    for (int i = tid; i < 4096; i += 512) {
        unsigned v = hist[i];
        if (v) atomicAdd(&gh[i], v);
    }
    __threadfence();
    if (tid == 0) lastv = atomicAdd(&ticket1[img], 1u);
    __syncthreads();
    if (lastv != 2047) return;

    // last block of this image: coarse scan of hist1 (atomic reads for coherence)
    unsigned loc[8], sum2 = 0;
    #pragma unroll
    for (int j = 0; j < 8; j++) { loc[j] = atomicAdd(&gh[tid * 8 + j], 0u); sum2 += loc[j]; }
    sc[tid] = sum2; __syncthreads();
    for (int off = 1; off < 512; off <<= 1) {
        unsigned t2 = (tid >= off) ? sc[tid - off] : 0; __syncthreads();
        sc[tid] += t2; __syncthreads();
    }
    unsigned incl = sc[tid], excl = incl - sum2;
    if (K_RANK >= excl && K_RANK < incl) {
        unsigned run = excl;
        #pragma unroll
        for (int j = 0; j < 8; j++) {
            if (K_RANK < run + loc[j]) { metaBin[img] = tid * 8 + j; metaBase[img] = (int)run; break; }
            run += loc[j];
        }
    }
}

// ---------------- P3: refine histogram (low 20 bits) for values in the selected bin
__global__ __launch_bounds__(256) void k_hist2(const float* __restrict__ R,
                                               const int* __restrict__ metaBin,
                                               unsigned* __restrict__ hist2)
{
    int img = blockIdx.x >> 10;                 // 1024 blocks per image
    unsigned b1 = (unsigned)metaBin[img];
    unsigned* h2 = hist2 + ((size_t)img << 20);
    const float4* __restrict__ R4 = (const float4*)R + (size_t)blockIdx.x * 1024;
    #pragma unroll
    for (int j = 0; j < 4; j++) {
        float4 v = R4[threadIdx.x + j * 256];
        unsigned ux = fmap(v.x), uy = fmap(v.y), uz = fmap(v.z), uw = fmap(v.w);
        if ((ux >> 20) == b1) atomicAdd(&h2[ux & 0xFFFFFu], 1u);
        if ((uy >> 20) == b1) atomicAdd(&h2[uy & 0xFFFFFu], 1u);
        if ((uz >> 20) == b1) atomicAdd(&h2[uz & 0xFFFFFu], 1u);
        if ((uw >> 20) == b1) atomicAdd(&h2[uw & 0xFFFFFu], 1u);
    }
}

// ---------------- P4: chunk sums + fused (last-block) exact median locate
__global__ __launch_bounds__(256) void k_med(const unsigned* __restrict__ hist2,
                                             unsigned* __restrict__ chunkSum,
                                             const int* __restrict__ metaBin,
                                             const int* __restrict__ metaBase,
                                             float* __restrict__ med,
                                             unsigned* __restrict__ ticket2)
{
    __shared__ unsigned s[256];
    __shared__ unsigned lastv;
    __shared__ int sel[2];
    const int tid = threadIdx.x;
    const int cb = blockIdx.x, img = blockIdx.y;

    const unsigned* h = hist2 + ((size_t)img << 20) + cb * 4096;
    unsigned sum = 0;
    #pragma unroll
    for (int j = 0; j < 16; j++) sum += h[tid + j * 256];
    s[tid] = sum; __syncthreads();
    for (int off = 128; off > 0; off >>= 1) {
        if (tid < off) s[tid] += s[tid + off];
        __syncthreads();
    }
    if (tid == 0) {
        atomicExch(&chunkSum[img * 256 + cb], s[0]);
        __threadfence();
        lastv = atomicAdd(ticket2, 1u);
    }
    __syncthreads();
    if (lastv != NIMG * 256 - 1) return;

    // final block: locate median for all images
    for (int im = 0; im < NIMG; im++) {
        unsigned target = K_RANK - (unsigned)metaBase[im];
        unsigned v = atomicAdd(&chunkSum[im * 256 + tid], 0u);
        __syncthreads();
        s[tid] = v; __syncthreads();
        for (int off = 1; off < 256; off <<= 1) {
            unsigned t2 = (tid >= off) ? s[tid - off] : 0; __syncthreads();
            s[tid] += t2; __syncthreads();
        }
        unsigned incl = s[tid], excl = incl - v;
        if (target >= excl && target < incl) { sel[0] = tid; sel[1] = (int)excl; }
        __syncthreads();
        int scb = sel[0];
        unsigned cexcl = (unsigned)sel[1];

        const unsigned* hh = hist2 + ((size_t)im << 20) + scb * 4096;
        unsigned loc[16], lsum = 0;
        #pragma unroll
        for (int j = 0; j < 16; j++) { loc[j] = hh[tid * 16 + j]; lsum += loc[j]; }
        __syncthreads();
        s[tid] = lsum; __syncthreads();
        for (int off = 1; off < 256; off <<= 1) {
            unsigned t2 = (tid >= off) ? s[tid - off] : 0; __syncthreads();
            s[tid] += t2; __syncthreads();
        }
        incl = s[tid] + cexcl; excl = s[tid] - lsum + cexcl;
        if (target >= excl && target < incl) {
            unsigned run = excl;
            #pragma unroll
            for (int j = 0; j < 16; j++) {
                if (target < run + loc[j]) {
                    unsigned c = (unsigned)scb * 4096u + (unsigned)tid * 16u + (unsigned)j;
                    unsigned mu = (((unsigned)metaBin[im]) << 20) | c;
                    unsigned fb = (mu & 0x80000000u) ? (mu & 0x7FFFFFFFu) : ~mu;
                    med[im] = __uint_as_float(fb);
                    break;
                }
                run += loc[j];
            }
        }
        __syncthreads();
    }
}

// ---------------- P5: threshold + separable 7x7 max-pool + equality write
__global__ __launch_bounds__(256) void k_out(const float* __restrict__ R,
                                             const float* __restrict__ med,
                                             float* __restrict__ out)
{
    __shared__ float rt[38][39];
    __shared__ float hm[38][33];
    const int tid = threadIdx.x;
    const int img = blockIdx.z;
    const int x0 = blockIdx.x * 32, y0 = blockIdx.y * 32;
    const float m = med[img];
    const float* __restrict__ Ri = R + ((size_t)img << 22);

    for (int i = tid; i < 1444; i += 256) {
        int r = i / 38, c = i - r * 38;
        int gy = y0 - 3 + r, gx = x0 - 3 + c;
        float v = -INFINITY;                      // reduce_window pad = -inf
        if ((unsigned)gy < H && (unsigned)gx < W) {
            float rv = Ri[(size_t)gy * W + gx];
            v = (rv >= m) ? rv : 0.0f;
        }
        rt[r][c] = v;
    }
    __syncthreads();

    for (int i = tid; i < 1216; i += 256) {
        int r = i >> 5, c = i & 31;
        float mx = rt[r][c];
        #pragma unroll
        for (int j = 1; j < 7; j++) mx = fmaxf(mx, rt[r][c + j]);
        hm[r][c] = mx;
    }
    __syncthreads();

    const int txc = tid & 31, ty0 = tid >> 5;
    float* __restrict__ Oi = out + ((size_t)img << 22);
    #pragma unroll
    for (int q = 0; q < 4; q++) {
        int ty = ty0 + q * 8;
        float mx = hm[ty][txc];
        #pragma unroll
        for (int j = 1; j < 7; j++) mx = fmaxf(mx, hm[ty + j][txc]);
        float c = rt[ty + 3][txc + 3];
        Oi[(size_t)(y0 + ty) * W + (x0 + txc)] = (c == mx) ? c : 0.0f;
    }
}

extern "C" void kernel_launch(void* const* d_in, const int* in_sizes, int n_in,
                              void* d_out, int out_size, void* d_ws, size_t ws_size,
                              hipStream_t stream)
{
    const float* x  = (const float*)d_in[0];
    const float* gk = (const float*)d_in[2];        // 7x7 gaussian (49 floats)
    float* out = (float*)d_out;

    char* ws = (char*)d_ws;
    float*    R        = (float*)ws;                                 // 64 MB
    unsigned* hist1    = (unsigned*)(ws + (size_t)HWPX * NIMG * 4);  // 64 KB
    unsigned* ticket1  = hist1 + NIMG * 4096;                        // 4 u32
    unsigned* ticket2  = ticket1 + 4;                                // 1 u32
    unsigned* chunkSum = ticket2 + 1;                                // 1024 u32
    int*      metaBin  = (int*)(chunkSum + 1024);                    // 4
    int*      metaBase = metaBin + NIMG;                             // 4
    float*    med      = (float*)(metaBase + NIMG);                  // 4
    double*   kwd      = (double*)(ws + (size_t)HWPX * NIMG * 4 + 71680); // 8B-aligned, past metas
    unsigned* hist2    = (unsigned*)d_out;                           // 16 MB scratch until k_out

    hipMemsetAsync(hist1, 0, (size_t)NIMG * 4096 * 4 + 32, stream);  // hist1 + tickets
    hipMemsetAsync(hist2, 0, (size_t)NIMG * (1u << 20) * 4, stream);

    k_prep    <<<1, 64, 0, stream>>>(gk, kwd);
    k_harris_R<<<dim3(32, 64, NIMG), 512, 0, stream>>>(x, kwd, R, hist1, ticket1, metaBin, metaBase);
    k_hist2   <<<4096, 256, 0, stream>>>(R, metaBin, hist2);
    k_med     <<<dim3(256, NIMG), 256, 0, stream>>>(hist2, chunkSum, metaBin, metaBase, med, ticket2);
    k_out     <<<dim3(64, 64, NIMG), 256, 0, stream>>>(R, med, out);
}

// Round 5
// 487.372 us; speedup vs baseline: 2.8083x; 2.8083x over previous
//
#include <hip/hip_runtime.h>

#define H 2048
#define W 2048
#define NIMG 4
#define HWPX (H*W)               // 4194304 = 2^22
#define K_RANK 2097151u          // (n-1)//2

__device__ __forceinline__ unsigned fmap(float f) {
    unsigned u = __float_as_uint(f);
    return (u & 0x80000000u) ? ~u : (u | 0x80000000u);
}

// ---------------- P0: convert f32 gaussian taps to f64 in ws
__global__ void k_prep(const float* __restrict__ gk, double* __restrict__ kwd) {
    int t = threadIdx.x;
    if (t < 49) kwd[t] = (double)gk[t];
}

// ---------------- P1: global-direct sobel -> ix/iy f64 in LDS -> 7x7 f64 conv (rolling
// products, round-3 op order) -> R(f32) + fused LDS histogram -> global hist1 merge.
// tile 64w x 32h, 512 threads, each thread 2 cols x 2 rows. LDS ~44KB -> 3 blocks/CU.
__global__ __launch_bounds__(512, 6) void k_harris_R(const float* __restrict__ x,
                                                     const double* __restrict__ kwd,
                                                     float* __restrict__ R,
                                                     unsigned* __restrict__ hist1)
{
    __align__(16) __shared__ double ixiy[5472];     // ix plane [38][72], iy plane [38][72]
    unsigned* hist = (unsigned*)ixiy;               // 16KB union, used after conv reads

    const int tid = threadIdx.x;
    const int img = blockIdx.z;
    const int x0 = blockIdx.x * 64, y0 = blockIdx.y * 32;
    const float* __restrict__ X = x + (size_t)img * HWPX;

    const bool interior = (x0 >= 4) && (x0 + 66 < W) && (y0 >= 4) && (y0 + 34 < H);

    if (interior) {
        for (int i = tid; i < 2736; i += 512) {     // 38*72
            int r = i / 72, c = i - r * 72;
            double ix = 0.0, iy = 0.0;
            if (c < 70) {
                const float* p = X + (size_t)(y0 - 4 + r) * W + (x0 - 4 + c);
                double x00 = p[0],     x01 = p[1],       x02 = p[2];
                double x10 = p[W],                        x12 = p[W + 2];
                double x20 = p[2 * W], x21 = p[2 * W + 1], x22 = p[2 * W + 2];
                ix = (x02 - x00) + 2.0 * (x12 - x10) + (x22 - x20);
                iy = (x20 - x00) + 2.0 * (x21 - x01) + (x22 - x02);
            }
            ixiy[i] = ix;
            ixiy[2736 + i] = iy;
        }
    } else {
        for (int i = tid; i < 2736; i += 512) {
            int r = i / 72, c = i - r * 72;
            double ix = 0.0, iy = 0.0;
            int gy = y0 - 3 + r, gx = x0 - 3 + c;
            if (c < 70 && (unsigned)gy < H && (unsigned)gx < W) {
                #define LD(yy, xx) ((((unsigned)(yy) < H) && ((unsigned)(xx) < W)) ? (double)X[(size_t)(yy) * W + (xx)] : 0.0)
                double x00 = LD(gy - 1, gx - 1), x01 = LD(gy - 1, gx), x02 = LD(gy - 1, gx + 1);
                double x10 = LD(gy,     gx - 1),                       x12 = LD(gy,     gx + 1);
                double x20 = LD(gy + 1, gx - 1), x21 = LD(gy + 1, gx), x22 = LD(gy + 1, gx + 1);
                #undef LD
                ix = (x02 - x00) + 2.0 * (x12 - x10) + (x22 - x20);
                iy = (x20 - x00) + 2.0 * (x21 - x01) + (x22 - x02);
            }
            ixiy[i] = ix;
            ixiy[2736 + i] = iy;
        }
    }
    __syncthreads();

    const int tc = (tid & 31) * 2;       // cols tc, tc+1 (0..62)
    const int tr = (tid >> 5) * 2;       // rows tr, tr+1 (0..30)

    double axx[2][2], ayy[2][2], axy[2][2];
    #pragma unroll
    for (int rr = 0; rr < 2; rr++)
        #pragma unroll
        for (int cc = 0; cc < 2; cc++) { axx[rr][cc] = 0.0; ayy[rr][cc] = 0.0; axy[rr][cc] = 0.0; }

    #pragma unroll
    for (int ii = 0; ii < 8; ii++) {
        const int prow = tr + ii;
        double vx[8], vy[8];
        const double2* rx = (const double2*)&ixiy[prow * 72 + tc];
        const double2* ry = (const double2*)&ixiy[2736 + prow * 72 + tc];
        #pragma unroll
        for (int q = 0; q < 4; q++) {
            double2 t = rx[q]; vx[2*q] = t.x; vx[2*q+1] = t.y;
            double2 u = ry[q]; vy[2*q] = u.x; vy[2*q+1] = u.y;
        }
        // rolling products: p = j for col0, p = j+1 for col1
        double xx0 = vx[0]*vx[0], yy0 = vy[0]*vy[0], xy0 = vx[0]*vy[0];
        #pragma unroll
        for (int j = 0; j < 7; j++) {
            double xx1 = vx[j+1]*vx[j+1], yy1 = vy[j+1]*vy[j+1], xy1 = vx[j+1]*vy[j+1];
            #pragma unroll
            for (int rr = 0; rr < 2; rr++) {
                const int wrow = ii - rr;
                if (wrow >= 0 && wrow <= 6) {
                    double w = kwd[wrow * 7 + j];
                    axx[rr][0] = fma(w, xx0, axx[rr][0]); axx[rr][1] = fma(w, xx1, axx[rr][1]);
                    ayy[rr][0] = fma(w, yy0, ayy[rr][0]); ayy[rr][1] = fma(w, yy1, ayy[rr][1]);
                    axy[rr][0] = fma(w, xy0, axy[rr][0]); axy[rr][1] = fma(w, xy1, axy[rr][1]);
                }
            }
            xx0 = xx1; yy0 = yy1; xy0 = xy1;
        }
    }

    float* __restrict__ Ri = R + (size_t)img * HWPX;
    unsigned bins[4];
    #pragma unroll
    for (int rr = 0; rr < 2; rr++) {
        float2 o;
        #pragma unroll
        for (int cc = 0; cc < 2; cc++) {
            double sxx = axx[rr][cc], syy = ayy[rr][cc], sxy = axy[rr][cc];
            double t2 = sxx + syy;
            double Rv = sxx * syy - sxy * sxy - 0.05 * t2 * t2;
            ((float*)&o)[cc] = (float)Rv;
        }
        *(float2*)&Ri[(size_t)(y0 + tr + rr) * W + (x0 + tc)] = o;
        bins[rr * 2]     = fmap(o.x) >> 20;
        bins[rr * 2 + 1] = fmap(o.y) >> 20;
    }
    __syncthreads();                               // all conv reads of ixiy done

    for (int i = tid; i < 4096; i += 512) hist[i] = 0;
    __syncthreads();
    #pragma unroll
    for (int q = 0; q < 4; q++) atomicAdd(&hist[bins[q]], 1u);
    __syncthreads();

    unsigned* gh = hist1 + img * 4096;
    for (int i = tid; i < 4096; i += 512) {
        unsigned v = hist[i];
        if (v) atomicAdd(&gh[i], v);
    }
}

// ---------------- P2: scan hist1 -> coarse bin + count below
__global__ __launch_bounds__(256) void k_scan1(const unsigned* __restrict__ hist1,
                                               int* __restrict__ metaBin,
                                               int* __restrict__ metaBase)
{
    int img = blockIdx.x, tid = threadIdx.x;
    __shared__ unsigned s[256];
    const unsigned* h = hist1 + img * 4096;
    unsigned loc[16], sum = 0;
    #pragma unroll
    for (int j = 0; j < 16; j++) { loc[j] = h[tid * 16 + j]; sum += loc[j]; }
    s[tid] = sum; __syncthreads();
    for (int off = 1; off < 256; off <<= 1) {
        unsigned v = (tid >= off) ? s[tid - off] : 0; __syncthreads();
        s[tid] += v; __syncthreads();
    }
    unsigned incl = s[tid], excl = incl - sum;
    if (K_RANK >= excl && K_RANK < incl) {
        unsigned run = excl;
        #pragma unroll
        for (int j = 0; j < 16; j++) {
            if (K_RANK < run + loc[j]) { metaBin[img] = tid * 16 + j; metaBase[img] = (int)run; break; }
            run += loc[j];
        }
    }
}

// ---------------- P3: refine histogram (low 20 bits) for values in the selected bin
__global__ __launch_bounds__(256) void k_hist2(const float* __restrict__ R,
                                               const int* __restrict__ metaBin,
                                               unsigned* __restrict__ hist2)
{
    int img = blockIdx.x >> 10;                 // 1024 blocks per image
    unsigned b1 = (unsigned)metaBin[img];
    unsigned* h2 = hist2 + ((size_t)img << 20);
    const float4* __restrict__ R4 = (const float4*)R + (size_t)blockIdx.x * 1024;
    #pragma unroll
    for (int j = 0; j < 4; j++) {
        float4 v = R4[threadIdx.x + j * 256];
        unsigned ux = fmap(v.x), uy = fmap(v.y), uz = fmap(v.z), uw = fmap(v.w);
        if ((ux >> 20) == b1) atomicAdd(&h2[ux & 0xFFFFFu], 1u);
        if ((uy >> 20) == b1) atomicAdd(&h2[uy & 0xFFFFFu], 1u);
        if ((uz >> 20) == b1) atomicAdd(&h2[uz & 0xFFFFFu], 1u);
        if ((uw >> 20) == b1) atomicAdd(&h2[uw & 0xFFFFFu], 1u);
    }
}

// ---------------- P4: chunk sums + fused (last-block) exact median locate
__global__ __launch_bounds__(256) void k_med(const unsigned* __restrict__ hist2,
                                             unsigned* __restrict__ chunkSum,
                                             const int* __restrict__ metaBin,
                                             const int* __restrict__ metaBase,
                                             float* __restrict__ med,
                                             unsigned* __restrict__ ticket2)
{
    __shared__ unsigned s[256];
    __shared__ unsigned lastv;
    __shared__ int sel[2];
    const int tid = threadIdx.x;
    const int cb = blockIdx.x, img = blockIdx.y;

    const unsigned* h = hist2 + ((size_t)img << 20) + cb * 4096;
    unsigned sum = 0;
    #pragma unroll
    for (int j = 0; j < 16; j++) sum += h[tid + j * 256];
    s[tid] = sum; __syncthreads();
    for (int off = 128; off > 0; off >>= 1) {
        if (tid < off) s[tid] += s[tid + off];
        __syncthreads();
    }
    if (tid == 0) {
        atomicExch(&chunkSum[img * 256 + cb], s[0]);
        __threadfence();
        lastv = atomicAdd(ticket2, 1u);
    }
    __syncthreads();
    if (lastv != NIMG * 256 - 1) return;

    // final block: locate median for all images
    for (int im = 0; im < NIMG; im++) {
        unsigned target = K_RANK - (unsigned)metaBase[im];
        unsigned v = atomicAdd(&chunkSum[im * 256 + tid], 0u);
        __syncthreads();
        s[tid] = v; __syncthreads();
        for (int off = 1; off < 256; off <<= 1) {
            unsigned t2 = (tid >= off) ? s[tid - off] : 0; __syncthreads();
            s[tid] += t2; __syncthreads();
        }
        unsigned incl = s[tid], excl = incl - v;
        if (target >= excl && target < incl) { sel[0] = tid; sel[1] = (int)excl; }
        __syncthreads();
        int scb = sel[0];
        unsigned cexcl = (unsigned)sel[1];

        const unsigned* hh = hist2 + ((size_t)im << 20) + scb * 4096;
        unsigned loc[16], lsum = 0;
        #pragma unroll
        for (int j = 0; j < 16; j++) { loc[j] = hh[tid * 16 + j]; lsum += loc[j]; }
        __syncthreads();
        s[tid] = lsum; __syncthreads();
        for (int off = 1; off < 256; off <<= 1) {
            unsigned t2 = (tid >= off) ? s[tid - off] : 0; __syncthreads();
            s[tid] += t2; __syncthreads();
        }
        incl = s[tid] + cexcl; excl = s[tid] - lsum + cexcl;
        if (target >= excl && target < incl) {
            unsigned run = excl;
            #pragma unroll
            for (int j = 0; j < 16; j++) {
                if (target < run + loc[j]) {
                    unsigned c = (unsigned)scb * 4096u + (unsigned)tid * 16u + (unsigned)j;
                    unsigned mu = (((unsigned)metaBin[im]) << 20) | c;
                    unsigned fb = (mu & 0x80000000u) ? (mu & 0x7FFFFFFFu) : ~mu;
                    med[im] = __uint_as_float(fb);
                    break;
                }
                run += loc[j];
            }
        }
        __syncthreads();
    }
}

// ---------------- P5: threshold + separable 7x7 max-pool + equality write
__global__ __launch_bounds__(256) void k_out(const float* __restrict__ R,
                                             const float* __restrict__ med,
                                             float* __restrict__ out)
{
    __shared__ float rt[38][39];
    __shared__ float hm[38][33];
    const int tid = threadIdx.x;
    const int img = blockIdx.z;
    const int x0 = blockIdx.x * 32, y0 = blockIdx.y * 32;
    const float m = med[img];
    const float* __restrict__ Ri = R + ((size_t)img << 22);

    for (int i = tid; i < 1444; i += 256) {
        int r = i / 38, c = i - r * 38;
        int gy = y0 - 3 + r, gx = x0 - 3 + c;
        float v = -INFINITY;                      // reduce_window pad = -inf
        if ((unsigned)gy < H && (unsigned)gx < W) {
            float rv = Ri[(size_t)gy * W + gx];
            v = (rv >= m) ? rv : 0.0f;
        }
        rt[r][c] = v;
    }
    __syncthreads();

    for (int i = tid; i < 1216; i += 256) {
        int r = i >> 5, c = i & 31;
        float mx = rt[r][c];
        #pragma unroll
        for (int j = 1; j < 7; j++) mx = fmaxf(mx, rt[r][c + j]);
        hm[r][c] = mx;
    }
    __syncthreads();

    const int txc = tid & 31, ty0 = tid >> 5;
    float* __restrict__ Oi = out + ((size_t)img << 22);
    #pragma unroll
    for (int q = 0; q < 4; q++) {
        int ty = ty0 + q * 8;
        float mx = hm[ty][txc];
        #pragma unroll
        for (int j = 1; j < 7; j++) mx = fmaxf(mx, hm[ty + j][txc]);
        float c = rt[ty + 3][txc + 3];
        Oi[(size_t)(y0 + ty) * W + (x0 + txc)] = (c == mx) ? c : 0.0f;
    }
}

extern "C" void kernel_launch(void* const* d_in, const int* in_sizes, int n_in,
                              void* d_out, int out_size, void* d_ws, size_t ws_size,
                              hipStream_t stream)
{
    const float* x  = (const float*)d_in[0];
    const float* gk = (const float*)d_in[2];        // 7x7 gaussian (49 floats)
    float* out = (float*)d_out;

    char* ws = (char*)d_ws;
    float*    R        = (float*)ws;                                 // 64 MB
    unsigned* hist1    = (unsigned*)(ws + (size_t)HWPX * NIMG * 4);  // 64 KB
    unsigned* ticket1  = hist1 + NIMG * 4096;                        // 4 u32 (unused)
    unsigned* ticket2  = ticket1 + 4;                                // 1 u32
    unsigned* chunkSum = ticket2 + 1;                                // 1024 u32
    int*      metaBin  = (int*)(chunkSum + 1024);                    // 4
    int*      metaBase = metaBin + NIMG;                             // 4
    float*    med      = (float*)(metaBase + NIMG);                  // 4
    double*   kwd      = (double*)(ws + (size_t)HWPX * NIMG * 4 + 71680); // 8B-aligned, past metas
    unsigned* hist2    = (unsigned*)d_out;                           // 16 MB scratch until k_out

    hipMemsetAsync(hist1, 0, (size_t)NIMG * 4096 * 4 + 32, stream);  // hist1 + tickets
    hipMemsetAsync(hist2, 0, (size_t)NIMG * (1u << 20) * 4, stream);

    k_prep    <<<1, 64, 0, stream>>>(gk, kwd);
    k_harris_R<<<dim3(32, 64, NIMG), 512, 0, stream>>>(x, kwd, R, hist1);
    k_scan1   <<<NIMG, 256, 0, stream>>>(hist1, metaBin, metaBase);
    k_hist2   <<<4096, 256, 0, stream>>>(R, metaBin, hist2);
    k_med     <<<dim3(256, NIMG), 256, 0, stream>>>(hist2, chunkSum, metaBin, metaBase, med, ticket2);
    k_out     <<<dim3(64, 64, NIMG), 256, 0, stream>>>(R, med, out);
}

// Round 6
// 391.042 us; speedup vs baseline: 3.5001x; 1.2463x over previous
//
#include <hip/hip_runtime.h>

#define H 2048
#define W 2048
#define NIMG 4
#define HWPX (H*W)               // 4194304 = 2^22
#define K_RANK 2097151u          // (n-1)//2

__device__ __forceinline__ unsigned fmap(float f) {
    unsigned u = __float_as_uint(f);
    return (u & 0x80000000u) ? ~u : (u | 0x80000000u);
}

// ---------------- P0: convert f32 gaussian taps to f64 in ws
__global__ void k_prep(const float* __restrict__ gk, double* __restrict__ kwd) {
    int t = threadIdx.x;
    if (t < 49) kwd[t] = (double)gk[t];
}

// ---------------- P1: global-direct sobel -> ix/iy f64 in LDS -> 7x7 f64 conv (rolling
// products, round-3 op order) -> R(f32) + fused LDS histogram -> global hist1 merge.
// tile 64w x 32h, 512 threads, each thread 2 cols x 2 rows. LDS ~44KB -> 3 blocks/CU.
// NOTE launch_bounds (512,4): (512,6) forced VGPR=40 -> scratch spill -> 702MB writes (round 5).
__global__ __launch_bounds__(512, 4) void k_harris_R(const float* __restrict__ x,
                                                     const double* __restrict__ kwd,
                                                     float* __restrict__ R,
                                                     unsigned* __restrict__ hist1)
{
    __align__(16) __shared__ double ixiy[5472];     // ix plane [38][72], iy plane [38][72]
    unsigned* hist = (unsigned*)ixiy;               // 16KB union, used after conv reads

    const int tid = threadIdx.x;
    const int img = blockIdx.z;
    const int x0 = blockIdx.x * 64, y0 = blockIdx.y * 32;
    const float* __restrict__ X = x + (size_t)img * HWPX;

    const bool interior = (x0 >= 4) && (x0 + 66 < W) && (y0 >= 4) && (y0 + 34 < H);

    if (interior) {
        for (int i = tid; i < 2736; i += 512) {     // 38*72
            int r = i / 72, c = i - r * 72;
            double ix = 0.0, iy = 0.0;
            if (c < 70) {
                const float* p = X + (size_t)(y0 - 4 + r) * W + (x0 - 4 + c);
                double x00 = p[0],     x01 = p[1],       x02 = p[2];
                double x10 = p[W],                        x12 = p[W + 2];
                double x20 = p[2 * W], x21 = p[2 * W + 1], x22 = p[2 * W + 2];
                ix = (x02 - x00) + 2.0 * (x12 - x10) + (x22 - x20);
                iy = (x20 - x00) + 2.0 * (x21 - x01) + (x22 - x02);
            }
            ixiy[i] = ix;
            ixiy[2736 + i] = iy;
        }
    } else {
        for (int i = tid; i < 2736; i += 512) {
            int r = i / 72, c = i - r * 72;
            double ix = 0.0, iy = 0.0;
            int gy = y0 - 3 + r, gx = x0 - 3 + c;
            if (c < 70 && (unsigned)gy < H && (unsigned)gx < W) {
                #define LD(yy, xx) ((((unsigned)(yy) < H) && ((unsigned)(xx) < W)) ? (double)X[(size_t)(yy) * W + (xx)] : 0.0)
                double x00 = LD(gy - 1, gx - 1), x01 = LD(gy - 1, gx), x02 = LD(gy - 1, gx + 1);
                double x10 = LD(gy,     gx - 1),                       x12 = LD(gy,     gx + 1);
                double x20 = LD(gy + 1, gx - 1), x21 = LD(gy + 1, gx), x22 = LD(gy + 1, gx + 1);
                #undef LD
                ix = (x02 - x00) + 2.0 * (x12 - x10) + (x22 - x20);
                iy = (x20 - x00) + 2.0 * (x21 - x01) + (x22 - x02);
            }
            ixiy[i] = ix;
            ixiy[2736 + i] = iy;
        }
    }
    __syncthreads();

    const int tc = (tid & 31) * 2;       // cols tc, tc+1 (0..62)
    const int tr = (tid >> 5) * 2;       // rows tr, tr+1 (0..30)

    double axx[2][2], ayy[2][2], axy[2][2];
    #pragma unroll
    for (int rr = 0; rr < 2; rr++)
        #pragma unroll
        for (int cc = 0; cc < 2; cc++) { axx[rr][cc] = 0.0; ayy[rr][cc] = 0.0; axy[rr][cc] = 0.0; }

    #pragma unroll
    for (int ii = 0; ii < 8; ii++) {
        const int prow = tr + ii;
        double vx[8], vy[8];
        const double2* rx = (const double2*)&ixiy[prow * 72 + tc];
        const double2* ry = (const double2*)&ixiy[2736 + prow * 72 + tc];
        #pragma unroll
        for (int q = 0; q < 4; q++) {
            double2 t = rx[q]; vx[2*q] = t.x; vx[2*q+1] = t.y;
            double2 u = ry[q]; vy[2*q] = u.x; vy[2*q+1] = u.y;
        }
        // rolling products: p = j for col0, p = j+1 for col1
        double xx0 = vx[0]*vx[0], yy0 = vy[0]*vy[0], xy0 = vx[0]*vy[0];
        #pragma unroll
        for (int j = 0; j < 7; j++) {
            double xx1 = vx[j+1]*vx[j+1], yy1 = vy[j+1]*vy[j+1], xy1 = vx[j+1]*vy[j+1];
            #pragma unroll
            for (int rr = 0; rr < 2; rr++) {
                const int wrow = ii - rr;
                if (wrow >= 0 && wrow <= 6) {
                    double w = kwd[wrow * 7 + j];
                    axx[rr][0] = fma(w, xx0, axx[rr][0]); axx[rr][1] = fma(w, xx1, axx[rr][1]);
                    ayy[rr][0] = fma(w, yy0, ayy[rr][0]); ayy[rr][1] = fma(w, yy1, ayy[rr][1]);
                    axy[rr][0] = fma(w, xy0, axy[rr][0]); axy[rr][1] = fma(w, xy1, axy[rr][1]);
                }
            }
            xx0 = xx1; yy0 = yy1; xy0 = xy1;
        }
    }

    float* __restrict__ Ri = R + (size_t)img * HWPX;
    unsigned bins[4];
    #pragma unroll
    for (int rr = 0; rr < 2; rr++) {
        float2 o;
        #pragma unroll
        for (int cc = 0; cc < 2; cc++) {
            double sxx = axx[rr][cc], syy = ayy[rr][cc], sxy = axy[rr][cc];
            double t2 = sxx + syy;
            double Rv = sxx * syy - sxy * sxy - 0.05 * t2 * t2;
            ((float*)&o)[cc] = (float)Rv;
        }
        *(float2*)&Ri[(size_t)(y0 + tr + rr) * W + (x0 + tc)] = o;
        bins[rr * 2]     = fmap(o.x) >> 20;
        bins[rr * 2 + 1] = fmap(o.y) >> 20;
    }
    __syncthreads();                               // all conv reads of ixiy done

    for (int i = tid; i < 4096; i += 512) hist[i] = 0;
    __syncthreads();
    #pragma unroll
    for (int q = 0; q < 4; q++) atomicAdd(&hist[bins[q]], 1u);
    __syncthreads();

    unsigned* gh = hist1 + img * 4096;
    for (int i = tid; i < 4096; i += 512) {
        unsigned v = hist[i];
        if (v) atomicAdd(&gh[i], v);
    }
}

// ---------------- P2: scan hist1 -> coarse bin + count below
__global__ __launch_bounds__(256) void k_scan1(const unsigned* __restrict__ hist1,
                                               int* __restrict__ metaBin,
                                               int* __restrict__ metaBase)
{
    int img = blockIdx.x, tid = threadIdx.x;
    __shared__ unsigned s[256];
    const unsigned* h = hist1 + img * 4096;
    unsigned loc[16], sum = 0;
    #pragma unroll
    for (int j = 0; j < 16; j++) { loc[j] = h[tid * 16 + j]; sum += loc[j]; }
    s[tid] = sum; __syncthreads();
    for (int off = 1; off < 256; off <<= 1) {
        unsigned v = (tid >= off) ? s[tid - off] : 0; __syncthreads();
        s[tid] += v; __syncthreads();
    }
    unsigned incl = s[tid], excl = incl - sum;
    if (K_RANK >= excl && K_RANK < incl) {
        unsigned run = excl;
        #pragma unroll
        for (int j = 0; j < 16; j++) {
            if (K_RANK < run + loc[j]) { metaBin[img] = tid * 16 + j; metaBase[img] = (int)run; break; }
            run += loc[j];
        }
    }
}

// ---------------- P3: refine histogram (low 20 bits) for values in the selected bin
__global__ __launch_bounds__(256) void k_hist2(const float* __restrict__ R,
                                               const int* __restrict__ metaBin,
                                               unsigned* __restrict__ hist2)
{
    int img = blockIdx.x >> 10;                 // 1024 blocks per image
    unsigned b1 = (unsigned)metaBin[img];
    unsigned* h2 = hist2 + ((size_t)img << 20);
    const float4* __restrict__ R4 = (const float4*)R + (size_t)blockIdx.x * 1024;
    #pragma unroll
    for (int j = 0; j < 4; j++) {
        float4 v = R4[threadIdx.x + j * 256];
        unsigned ux = fmap(v.x), uy = fmap(v.y), uz = fmap(v.z), uw = fmap(v.w);
        if ((ux >> 20) == b1) atomicAdd(&h2[ux & 0xFFFFFu], 1u);
        if ((uy >> 20) == b1) atomicAdd(&h2[uy & 0xFFFFFu], 1u);
        if ((uz >> 20) == b1) atomicAdd(&h2[uz & 0xFFFFFu], 1u);
        if ((uw >> 20) == b1) atomicAdd(&h2[uw & 0xFFFFFu], 1u);
    }
}

// ---------------- P4: chunk sums + fused (last-block) exact median locate
__global__ __launch_bounds__(256) void k_med(const unsigned* __restrict__ hist2,
                                             unsigned* __restrict__ chunkSum,
                                             const int* __restrict__ metaBin,
                                             const int* __restrict__ metaBase,
                                             float* __restrict__ med,
                                             unsigned* __restrict__ ticket2)
{
    __shared__ unsigned s[256];
    __shared__ unsigned lastv;
    __shared__ int sel[2];
    const int tid = threadIdx.x;
    const int cb = blockIdx.x, img = blockIdx.y;

    const unsigned* h = hist2 + ((size_t)img << 20) + cb * 4096;
    unsigned sum = 0;
    #pragma unroll
    for (int j = 0; j < 16; j++) sum += h[tid + j * 256];
    s[tid] = sum; __syncthreads();
    for (int off = 128; off > 0; off >>= 1) {
        if (tid < off) s[tid] += s[tid + off];
        __syncthreads();
    }
    if (tid == 0) {
        atomicExch(&chunkSum[img * 256 + cb], s[0]);
        __threadfence();
        lastv = atomicAdd(ticket2, 1u);
    }
    __syncthreads();
    if (lastv != NIMG * 256 - 1) return;

    // final block: locate median for all images
    for (int im = 0; im < NIMG; im++) {
        unsigned target = K_RANK - (unsigned)metaBase[im];
        unsigned v = atomicAdd(&chunkSum[im * 256 + tid], 0u);
        __syncthreads();
        s[tid] = v; __syncthreads();
        for (int off = 1; off < 256; off <<= 1) {
            unsigned t2 = (tid >= off) ? s[tid - off] : 0; __syncthreads();
            s[tid] += t2; __syncthreads();
        }
        unsigned incl = s[tid], excl = incl - v;
        if (target >= excl && target < incl) { sel[0] = tid; sel[1] = (int)excl; }
        __syncthreads();
        int scb = sel[0];
        unsigned cexcl = (unsigned)sel[1];

        const unsigned* hh = hist2 + ((size_t)im << 20) + scb * 4096;
        unsigned loc[16], lsum = 0;
        #pragma unroll
        for (int j = 0; j < 16; j++) { loc[j] = hh[tid * 16 + j]; lsum += loc[j]; }
        __syncthreads();
        s[tid] = lsum; __syncthreads();
        for (int off = 1; off < 256; off <<= 1) {
            unsigned t2 = (tid >= off) ? s[tid - off] : 0; __syncthreads();
            s[tid] += t2; __syncthreads();
        }
        incl = s[tid] + cexcl; excl = s[tid] - lsum + cexcl;
        if (target >= excl && target < incl) {
            unsigned run = excl;
            #pragma unroll
            for (int j = 0; j < 16; j++) {
                if (target < run + loc[j]) {
                    unsigned c = (unsigned)scb * 4096u + (unsigned)tid * 16u + (unsigned)j;
                    unsigned mu = (((unsigned)metaBin[im]) << 20) | c;
                    unsigned fb = (mu & 0x80000000u) ? (mu & 0x7FFFFFFFu) : ~mu;
                    med[im] = __uint_as_float(fb);
                    break;
                }
                run += loc[j];
            }
        }
        __syncthreads();
    }
}

// ---------------- P5: threshold + separable 7x7 max-pool + equality write
__global__ __launch_bounds__(256) void k_out(const float* __restrict__ R,
                                             const float* __restrict__ med,
                                             float* __restrict__ out)
{
    __shared__ float rt[38][39];
    __shared__ float hm[38][33];
    const int tid = threadIdx.x;
    const int img = blockIdx.z;
    const int x0 = blockIdx.x * 32, y0 = blockIdx.y * 32;
    const float m = med[img];
    const float* __restrict__ Ri = R + ((size_t)img << 22);

    for (int i = tid; i < 1444; i += 256) {
        int r = i / 38, c = i - r * 38;
        int gy = y0 - 3 + r, gx = x0 - 3 + c;
        float v = -INFINITY;                      // reduce_window pad = -inf
        if ((unsigned)gy < H && (unsigned)gx < W) {
            float rv = Ri[(size_t)gy * W + gx];
            v = (rv >= m) ? rv : 0.0f;
        }
        rt[r][c] = v;
    }
    __syncthreads();

    for (int i = tid; i < 1216; i += 256) {
        int r = i >> 5, c = i & 31;
        float mx = rt[r][c];
        #pragma unroll
        for (int j = 1; j < 7; j++) mx = fmaxf(mx, rt[r][c + j]);
        hm[r][c] = mx;
    }
    __syncthreads();

    const int txc = tid & 31, ty0 = tid >> 5;
    float* __restrict__ Oi = out + ((size_t)img << 22);
    #pragma unroll
    for (int q = 0; q < 4; q++) {
        int ty = ty0 + q * 8;
        float mx = hm[ty][txc];
        #pragma unroll
        for (int j = 1; j < 7; j++) mx = fmaxf(mx, hm[ty + j][txc]);
        float c = rt[ty + 3][txc + 3];
        Oi[(size_t)(y0 + ty) * W + (x0 + txc)] = (c == mx) ? c : 0.0f;
    }
}

extern "C" void kernel_launch(void* const* d_in, const int* in_sizes, int n_in,
                              void* d_out, int out_size, void* d_ws, size_t ws_size,
                              hipStream_t stream)
{
    const float* x  = (const float*)d_in[0];
    const float* gk = (const float*)d_in[2];        // 7x7 gaussian (49 floats)
    float* out = (float*)d_out;

    char* ws = (char*)d_ws;
    float*    R        = (float*)ws;                                 // 64 MB
    unsigned* hist1    = (unsigned*)(ws + (size_t)HWPX * NIMG * 4);  // 64 KB
    unsigned* ticket1  = hist1 + NIMG * 4096;                        // 4 u32 (unused)
    unsigned* ticket2  = ticket1 + 4;                                // 1 u32
    unsigned* chunkSum = ticket2 + 1;                                // 1024 u32
    int*      metaBin  = (int*)(chunkSum + 1024);                    // 4
    int*      metaBase = metaBin + NIMG;                             // 4
    float*    med      = (float*)(metaBase + NIMG);                  // 4
    double*   kwd      = (double*)(ws + (size_t)HWPX * NIMG * 4 + 71680); // 8B-aligned, past metas
    unsigned* hist2    = (unsigned*)d_out;                           // 16 MB scratch until k_out

    hipMemsetAsync(hist1, 0, (size_t)NIMG * 4096 * 4 + 32, stream);  // hist1 + tickets
    hipMemsetAsync(hist2, 0, (size_t)NIMG * (1u << 20) * 4, stream);

    k_prep    <<<1, 64, 0, stream>>>(gk, kwd);
    k_harris_R<<<dim3(32, 64, NIMG), 512, 0, stream>>>(x, kwd, R, hist1);
    k_scan1   <<<NIMG, 256, 0, stream>>>(hist1, metaBin, metaBase);
    k_hist2   <<<4096, 256, 0, stream>>>(R, metaBin, hist2);
    k_med     <<<dim3(256, NIMG), 256, 0, stream>>>(hist2, chunkSum, metaBin, metaBase, med, ticket2);
    k_out     <<<dim3(64, 64, NIMG), 256, 0, stream>>>(R, med, out);
}

// Round 8
// 304.936 us; speedup vs baseline: 4.4884x; 1.2824x over previous
//
#include <hip/hip_runtime.h>

#define H 2048
#define W 2048
#define NIMG 4
#define HWPX (H*W)               // 4194304 = 2^22
#define K_RANK 2097151u          // (n-1)//2

__device__ __forceinline__ unsigned fmap(float f) {
    unsigned u = __float_as_uint(f);
    return (u & 0x80000000u) ? ~u : (u | 0x80000000u);
}

// ---------------- P0: convert f32 gaussian taps to f64 in ws
__global__ void k_prep(const float* __restrict__ gk, double* __restrict__ kwd) {
    int t = threadIdx.x;
    if (t < 49) kwd[t] = (double)gk[t];
}

// ---------------- P1: xs f32 stage (stride 72 — 72 cols NEEDED, round-7's stride-71 aliased
// rows) -> sobel -> ix/iy f64 in LDS (stride 70) -> 7x7 f64 conv (rolling products,
// round-3 bit-exact order) -> R(f32) + fused LDS hist.
// tile 64w x 32h, 512 threads, 2 cols x 2 rows each. LDS 54080+256B -> 3 blocks/CU.
// NOTE launch_bounds (512,4): (512,6) forced VGPR=40 -> scratch spill -> 702MB writes (round 5).
__global__ __launch_bounds__(512, 4) void k_harris_R(const float* __restrict__ x,
                                                     const double* __restrict__ kwd,
                                                     float* __restrict__ R,
                                                     unsigned* __restrict__ hist1)
{
    __align__(16) __shared__ double ixiy[5320];     // ix plane [38][70], iy plane [38][70]
    __shared__ float xs[2880];                      // [40][72], rows y0-4..y0+35, cols x0-4..x0+67
    unsigned* hist = (unsigned*)ixiy;               // 16KB union, used after conv reads

    const int tid = threadIdx.x;
    const int img = blockIdx.z;
    const int x0 = blockIdx.x * 64, y0 = blockIdx.y * 32;
    const float* __restrict__ X = x + (size_t)img * HWPX;

    // stage x tile with halo 4 (zero-padded)
    for (int i = tid; i < 2880; i += 512) {         // 40*72
        int r = i / 72, c = i - r * 72;
        int gy = y0 - 4 + r, gx = x0 - 4 + c;
        float v = 0.f;
        if ((unsigned)gy < H && (unsigned)gx < W) v = X[(size_t)gy * W + gx];
        xs[i] = v;
    }
    __syncthreads();

    // sobel in f64 from xs: plane rows 0..37 (image rows y0-3..), cols 0..69 (x0-3..)
    for (int i = tid; i < 2660; i += 512) {         // 38*70
        int r = i / 70, c = i - r * 70;
        double ix = 0.0, iy = 0.0;
        int gy = y0 - 3 + r, gx = x0 - 3 + c;
        if ((unsigned)gy < H && (unsigned)gx < W) {
            const float* p0 = &xs[r * 72 + c];
            double x00 = p0[0],   x01 = p0[1],   x02 = p0[2];
            double x10 = p0[72],                  x12 = p0[74];
            double x20 = p0[144], x21 = p0[145], x22 = p0[146];
            ix = (x02 - x00) + 2.0 * (x12 - x10) + (x22 - x20);
            iy = (x20 - x00) + 2.0 * (x21 - x01) + (x22 - x02);
        }
        ixiy[i] = ix;
        ixiy[2660 + i] = iy;
    }
    __syncthreads();

    const int tc = (tid & 31) * 2;       // cols tc, tc+1 (0..62)
    const int tr = (tid >> 5) * 2;       // rows tr, tr+1 (0..30)

    double axx[2][2], ayy[2][2], axy[2][2];
    #pragma unroll
    for (int rr = 0; rr < 2; rr++)
        #pragma unroll
        for (int cc = 0; cc < 2; cc++) { axx[rr][cc] = 0.0; ayy[rr][cc] = 0.0; axy[rr][cc] = 0.0; }

    #pragma unroll
    for (int ii = 0; ii < 8; ii++) {
        const int prow = tr + ii;
        double vx[8], vy[8];
        const double2* rx = (const double2*)&ixiy[prow * 70 + tc];
        const double2* ry = (const double2*)&ixiy[2660 + prow * 70 + tc];
        #pragma unroll
        for (int q = 0; q < 4; q++) {
            double2 t = rx[q]; vx[2*q] = t.x; vx[2*q+1] = t.y;
            double2 u = ry[q]; vy[2*q] = u.x; vy[2*q+1] = u.y;
        }
        // rolling products: p = j for col0, p = j+1 for col1
        double xx0 = vx[0]*vx[0], yy0 = vy[0]*vy[0], xy0 = vx[0]*vy[0];
        #pragma unroll
        for (int j = 0; j < 7; j++) {
            double xx1 = vx[j+1]*vx[j+1], yy1 = vy[j+1]*vy[j+1], xy1 = vx[j+1]*vy[j+1];
            #pragma unroll
            for (int rr = 0; rr < 2; rr++) {
                const int wrow = ii - rr;
                if (wrow >= 0 && wrow <= 6) {
                    double w = kwd[wrow * 7 + j];
                    axx[rr][0] = fma(w, xx0, axx[rr][0]); axx[rr][1] = fma(w, xx1, axx[rr][1]);
                    ayy[rr][0] = fma(w, yy0, ayy[rr][0]); ayy[rr][1] = fma(w, yy1, ayy[rr][1]);
                    axy[rr][0] = fma(w, xy0, axy[rr][0]); axy[rr][1] = fma(w, xy1, axy[rr][1]);
                }
            }
            xx0 = xx1; yy0 = yy1; xy0 = xy1;
        }
    }

    float* __restrict__ Ri = R + (size_t)img * HWPX;
    unsigned bins[4];
    #pragma unroll
    for (int rr = 0; rr < 2; rr++) {
        float2 o;
        #pragma unroll
        for (int cc = 0; cc < 2; cc++) {
            double sxx = axx[rr][cc], syy = ayy[rr][cc], sxy = axy[rr][cc];
            double t2 = sxx + syy;
            double Rv = sxx * syy - sxy * sxy - 0.05 * t2 * t2;
            ((float*)&o)[cc] = (float)Rv;
        }
        *(float2*)&Ri[(size_t)(y0 + tr + rr) * W + (x0 + tc)] = o;
        bins[rr * 2]     = fmap(o.x) >> 20;
        bins[rr * 2 + 1] = fmap(o.y) >> 20;
    }
    __syncthreads();                               // all conv reads of ixiy done

    for (int i = tid; i < 4096; i += 512) hist[i] = 0;
    __syncthreads();
    #pragma unroll
    for (int q = 0; q < 4; q++) atomicAdd(&hist[bins[q]], 1u);
    __syncthreads();

    unsigned* gh = hist1 + img * 4096;
    for (int i = tid; i < 4096; i += 512) {
        unsigned v = hist[i];
        if (v) atomicAdd(&gh[i], v);
    }
}

// ---------------- P2: scan hist1 -> coarse bin + count below
__global__ __launch_bounds__(256) void k_scan1(const unsigned* __restrict__ hist1,
                                               int* __restrict__ metaBin,
                                               int* __restrict__ metaBase)
{
    int img = blockIdx.x, tid = threadIdx.x;
    __shared__ unsigned s[256];
    const unsigned* h = hist1 + img * 4096;
    unsigned loc[16], sum = 0;
    #pragma unroll
    for (int j = 0; j < 16; j++) { loc[j] = h[tid * 16 + j]; sum += loc[j]; }
    s[tid] = sum; __syncthreads();
    for (int off = 1; off < 256; off <<= 1) {
        unsigned v = (tid >= off) ? s[tid - off] : 0; __syncthreads();
        s[tid] += v; __syncthreads();
    }
    unsigned incl = s[tid], excl = incl - sum;
    if (K_RANK >= excl && K_RANK < incl) {
        unsigned run = excl;
        #pragma unroll
        for (int j = 0; j < 16; j++) {
            if (K_RANK < run + loc[j]) { metaBin[img] = tid * 16 + j; metaBase[img] = (int)run; break; }
            run += loc[j];
        }
    }
}

// ---------------- P3: refine histogram (low 20 bits) for values in the selected bin
__global__ __launch_bounds__(256) void k_hist2(const float* __restrict__ R,
                                               const int* __restrict__ metaBin,
                                               unsigned* __restrict__ hist2)
{
    int img = blockIdx.x >> 10;                 // 1024 blocks per image
    unsigned b1 = (unsigned)metaBin[img];
    unsigned* h2 = hist2 + ((size_t)img << 20);
    const float4* __restrict__ R4 = (const float4*)R + (size_t)blockIdx.x * 1024;
    #pragma unroll
    for (int j = 0; j < 4; j++) {
        float4 v = R4[threadIdx.x + j * 256];
        unsigned ux = fmap(v.x), uy = fmap(v.y), uz = fmap(v.z), uw = fmap(v.w);
        if ((ux >> 20) == b1) atomicAdd(&h2[ux & 0xFFFFFu], 1u);
        if ((uy >> 20) == b1) atomicAdd(&h2[uy & 0xFFFFFu], 1u);
        if ((uz >> 20) == b1) atomicAdd(&h2[uz & 0xFFFFFu], 1u);
        if ((uw >> 20) == b1) atomicAdd(&h2[uw & 0xFFFFFu], 1u);
    }
}

// ---------------- P4: chunk sums + fused (last-block) exact median locate
__global__ __launch_bounds__(256) void k_med(const unsigned* __restrict__ hist2,
                                             unsigned* __restrict__ chunkSum,
                                             const int* __restrict__ metaBin,
                                             const int* __restrict__ metaBase,
                                             float* __restrict__ med,
                                             unsigned* __restrict__ ticket2)
{
    __shared__ unsigned s[256];
    __shared__ unsigned lastv;
    __shared__ int sel[2];
    const int tid = threadIdx.x;
    const int cb = blockIdx.x, img = blockIdx.y;

    const unsigned* h = hist2 + ((size_t)img << 20) + cb * 4096;
    unsigned sum = 0;
    #pragma unroll
    for (int j = 0; j < 16; j++) sum += h[tid + j * 256];
    s[tid] = sum; __syncthreads();
    for (int off = 128; off > 0; off >>= 1) {
        if (tid < off) s[tid] += s[tid + off];
        __syncthreads();
    }
    if (tid == 0) {
        atomicExch(&chunkSum[img * 256 + cb], s[0]);
        __threadfence();
        lastv = atomicAdd(ticket2, 1u);
    }
    __syncthreads();
    if (lastv != NIMG * 256 - 1) return;

    // final block: locate median for all images
    for (int im = 0; im < NIMG; im++) {
        unsigned target = K_RANK - (unsigned)metaBase[im];
        unsigned v = atomicAdd(&chunkSum[im * 256 + tid], 0u);
        __syncthreads();
        s[tid] = v; __syncthreads();
        for (int off = 1; off < 256; off <<= 1) {
            unsigned t2 = (tid >= off) ? s[tid - off] : 0; __syncthreads();
            s[tid] += t2; __syncthreads();
        }
        unsigned incl = s[tid], excl = incl - v;
        if (target >= excl && target < incl) { sel[0] = tid; sel[1] = (int)excl; }
        __syncthreads();
        int scb = sel[0];
        unsigned cexcl = (unsigned)sel[1];

        const unsigned* hh = hist2 + ((size_t)im << 20) + scb * 4096;
        unsigned loc[16], lsum = 0;
        #pragma unroll
        for (int j = 0; j < 16; j++) { loc[j] = hh[tid * 16 + j]; lsum += loc[j]; }
        __syncthreads();
        s[tid] = lsum; __syncthreads();
        for (int off = 1; off < 256; off <<= 1) {
            unsigned t2 = (tid >= off) ? s[tid - off] : 0; __syncthreads();
            s[tid] += t2; __syncthreads();
        }
        incl = s[tid] + cexcl; excl = s[tid] - lsum + cexcl;
        if (target >= excl && target < incl) {
            unsigned run = excl;
            #pragma unroll
            for (int j = 0; j < 16; j++) {
                if (target < run + loc[j]) {
                    unsigned c = (unsigned)scb * 4096u + (unsigned)tid * 16u + (unsigned)j;
                    unsigned mu = (((unsigned)metaBin[im]) << 20) | c;
                    unsigned fb = (mu & 0x80000000u) ? (mu & 0x7FFFFFFFu) : ~mu;
                    med[im] = __uint_as_float(fb);
                    break;
                }
                run += loc[j];
            }
        }
        __syncthreads();
    }
}

// ---------------- P5: threshold + separable 7x7 max-pool + equality write
__global__ __launch_bounds__(256) void k_out(const float* __restrict__ R,
                                             const float* __restrict__ med,
                                             float* __restrict__ out)
{
    __shared__ float rt[38][39];
    __shared__ float hm[38][33];
    const int tid = threadIdx.x;
    const int img = blockIdx.z;
    const int x0 = blockIdx.x * 32, y0 = blockIdx.y * 32;
    const float m = med[img];
    const float* __restrict__ Ri = R + ((size_t)img << 22);

    for (int i = tid; i < 1444; i += 256) {
        int r = i / 38, c = i - r * 38;
        int gy = y0 - 3 + r, gx = x0 - 3 + c;
        float v = -INFINITY;                      // reduce_window pad = -inf
        if ((unsigned)gy < H && (unsigned)gx < W) {
            float rv = Ri[(size_t)gy * W + gx];
            v = (rv >= m) ? rv : 0.0f;
        }
        rt[r][c] = v;
    }
    __syncthreads();

    for (int i = tid; i < 1216; i += 256) {
        int r = i >> 5, c = i & 31;
        float mx = rt[r][c];
        #pragma unroll
        for (int j = 1; j < 7; j++) mx = fmaxf(mx, rt[r][c + j]);
        hm[r][c] = mx;
    }
    __syncthreads();

    const int txc = tid & 31, ty0 = tid >> 5;
    float* __restrict__ Oi = out + ((size_t)img << 22);
    #pragma unroll
    for (int q = 0; q < 4; q++) {
        int ty = ty0 + q * 8;
        float mx = hm[ty][txc];
        #pragma unroll
        for (int j = 1; j < 7; j++) mx = fmaxf(mx, hm[ty + j][txc]);
        float c = rt[ty + 3][txc + 3];
        Oi[(size_t)(y0 + ty) * W + (x0 + txc)] = (c == mx) ? c : 0.0f;
    }
}

extern "C" void kernel_launch(void* const* d_in, const int* in_sizes, int n_in,
                              void* d_out, int out_size, void* d_ws, size_t ws_size,
                              hipStream_t stream)
{
    const float* x  = (const float*)d_in[0];
    const float* gk = (const float*)d_in[2];        // 7x7 gaussian (49 floats)
    float* out = (float*)d_out;

    char* ws = (char*)d_ws;
    float*    R        = (float*)ws;                                 // 64 MB
    unsigned* hist1    = (unsigned*)(ws + (size_t)HWPX * NIMG * 4);  // 64 KB
    unsigned* ticket1  = hist1 + NIMG * 4096;                        // 4 u32 (unused)
    unsigned* ticket2  = ticket1 + 4;                                // 1 u32
    unsigned* chunkSum = ticket2 + 1;                                // 1024 u32
    int*      metaBin  = (int*)(chunkSum + 1024);                    // 4
    int*      metaBase = metaBin + NIMG;                             // 4
    float*    med      = (float*)(metaBase + NIMG);                  // 4
    double*   kwd      = (double*)(ws + (size_t)HWPX * NIMG * 4 + 71680); // 8B-aligned, past metas
    unsigned* hist2    = (unsigned*)d_out;                           // 16 MB scratch until k_out

    hipMemsetAsync(hist1, 0, (size_t)NIMG * 4096 * 4 + 32, stream);  // hist1 + tickets
    hipMemsetAsync(hist2, 0, (size_t)NIMG * (1u << 20) * 4, stream);

    k_prep    <<<1, 64, 0, stream>>>(gk, kwd);
    k_harris_R<<<dim3(32, 64, NIMG), 512, 0, stream>>>(x, kwd, R, hist1);
    k_scan1   <<<NIMG, 256, 0, stream>>>(hist1, metaBin, metaBase);
    k_hist2   <<<4096, 256, 0, stream>>>(R, metaBin, hist2);
    k_med     <<<dim3(256, NIMG), 256, 0, stream>>>(hist2, chunkSum, metaBin, metaBase, med, ticket2);
    k_out     <<<dim3(64, 64, NIMG), 256, 0, stream>>>(R, med, out);
}

// Round 9
// 281.674 us; speedup vs baseline: 4.8591x; 1.0826x over previous
//
#include <hip/hip_runtime.h>

#define H 2048
#define W 2048
#define NIMG 4
#define HWPX (H*W)               // 4194304 = 2^22
#define K_RANK 2097151u          // (n-1)//2

__device__ __forceinline__ unsigned fmap(float f) {
    unsigned u = __float_as_uint(f);
    return (u & 0x80000000u) ? ~u : (u | 0x80000000u);
}

// ---------------- P0: convert gaussian taps to f64 + zero hist1/tickets (replaces memset)
__global__ __launch_bounds__(512) void k_prep(const float* __restrict__ gk,
                                              double* __restrict__ kwd,
                                              unsigned* __restrict__ hist1z)
{
    int t = blockIdx.x * 512 + threadIdx.x;      // grid 32*512 = 16384
    if (t < 49) kwd[t] = (double)gk[t];
    hist1z[t] = 0u;                              // hist1: 16384 u32
    if (t < 8) hist1z[16384 + t] = 0u;           // ticket1[4] + ticket2[1] + pad
}

// ---------------- P1: xs f32 stage -> sobel -> 3 f64 PRODUCT planes in LDS (stride 70)
// -> direct 7x7 f64 conv from planes (round-2-proven bit-exact chain order) -> R(f32)
// + fused LDS hist + zero-my-slice of hist2 (replaces 16MB memset).
// tile 64w x 32h, 512 threads, 2 cols x 2 rows each. LDS 75.4KB -> 2 blocks/CU.
// NOTE launch_bounds (512,4): (512,6) forced VGPR=40 -> scratch spill -> 702MB writes (round 5).
__global__ __launch_bounds__(512, 4) void k_harris_R(const float* __restrict__ x,
                                                     const double* __restrict__ kwd,
                                                     float* __restrict__ R,
                                                     unsigned* __restrict__ hist1,
                                                     unsigned* __restrict__ hist2z)
{
    __align__(16) __shared__ double prods[7980];    // 3 planes [38][70] f64
    __shared__ float xs[2880];                      // [40][72], rows y0-4..y0+35, cols x0-4..x0+67
    unsigned* hist = (unsigned*)prods;              // 16KB union, used after conv reads

    const int tid = threadIdx.x;
    const int img = blockIdx.z;
    const int x0 = blockIdx.x * 64, y0 = blockIdx.y * 32;
    const float* __restrict__ X = x + (size_t)img * HWPX;

    // zero this block's 2KB slice of hist2 (16MB / 8192 blocks = 512 u32)
    {
        int bidlin = ((img * gridDim.y) + blockIdx.y) * gridDim.x + blockIdx.x;
        hist2z[(size_t)bidlin * 512 + tid] = 0u;
    }

    // stage x tile with halo 4 (zero-padded)
    for (int i = tid; i < 2880; i += 512) {         // 40*72
        int r = i / 72, c = i - r * 72;
        int gy = y0 - 4 + r, gx = x0 - 4 + c;
        float v = 0.f;
        if ((unsigned)gy < H && (unsigned)gx < W) v = X[(size_t)gy * W + gx];
        xs[i] = v;
    }
    __syncthreads();

    // sobel in f64 from xs + products, staged once per plane pixel
    for (int i = tid; i < 2660; i += 512) {         // 38*70
        int r = i / 70, c = i - r * 70;
        double pxx = 0.0, pyy = 0.0, pxy = 0.0;
        int gy = y0 - 3 + r, gx = x0 - 3 + c;
        if ((unsigned)gy < H && (unsigned)gx < W) {
            const float* p0 = &xs[r * 72 + c];
            double x00 = p0[0],   x01 = p0[1],   x02 = p0[2];
            double x10 = p0[72],                  x12 = p0[74];
            double x20 = p0[144], x21 = p0[145], x22 = p0[146];
            double ix = (x02 - x00) + 2.0 * (x12 - x10) + (x22 - x20);
            double iy = (x20 - x00) + 2.0 * (x21 - x01) + (x22 - x02);
            pxx = ix * ix; pyy = iy * iy; pxy = ix * iy;
        }
        prods[i] = pxx;
        prods[2660 + i] = pyy;
        prods[5320 + i] = pxy;
    }
    __syncthreads();

    const int tc = (tid & 31) * 2;       // cols tc, tc+1 (0..62)
    const int tr = (tid >> 5) * 2;       // rows tr, tr+1 (0..30)

    double acc[3][2][2];
    #pragma unroll
    for (int ch = 0; ch < 3; ch++)
        #pragma unroll
        for (int rr = 0; rr < 2; rr++) { acc[ch][rr][0] = 0.0; acc[ch][rr][1] = 0.0; }

    #pragma unroll
    for (int ii = 0; ii < 8; ii++) {
        const int pr = tr + ii;
        #pragma unroll
        for (int ch = 0; ch < 3; ch++) {
            double pv[8];
            const double2* prow = (const double2*)&prods[ch * 2660 + pr * 70 + tc];
            #pragma unroll
            for (int q = 0; q < 4; q++) { double2 t = prow[q]; pv[2*q] = t.x; pv[2*q+1] = t.y; }
            if (ii <= 6) {                       // output row 0, weight row ii
                #pragma unroll
                for (int j = 0; j < 7; j++) {
                    double w = kwd[ii * 7 + j];
                    acc[ch][0][0] = fma(w, pv[j],   acc[ch][0][0]);
                    acc[ch][0][1] = fma(w, pv[j+1], acc[ch][0][1]);
                }
            }
            if (ii >= 1) {                       // output row 1, weight row ii-1
                #pragma unroll
                for (int j = 0; j < 7; j++) {
                    double w = kwd[(ii - 1) * 7 + j];
                    acc[ch][1][0] = fma(w, pv[j],   acc[ch][1][0]);
                    acc[ch][1][1] = fma(w, pv[j+1], acc[ch][1][1]);
                }
            }
        }
    }

    float* __restrict__ Ri = R + (size_t)img * HWPX;
    unsigned bins[4];
    #pragma unroll
    for (int rr = 0; rr < 2; rr++) {
        float2 o;
        #pragma unroll
        for (int cc = 0; cc < 2; cc++) {
            double sxx = acc[0][rr][cc], syy = acc[1][rr][cc], sxy = acc[2][rr][cc];
            double t2 = sxx + syy;
            double Rv = sxx * syy - sxy * sxy - 0.05 * t2 * t2;
            ((float*)&o)[cc] = (float)Rv;
        }
        *(float2*)&Ri[(size_t)(y0 + tr + rr) * W + (x0 + tc)] = o;
        bins[rr * 2]     = fmap(o.x) >> 20;
        bins[rr * 2 + 1] = fmap(o.y) >> 20;
    }
    __syncthreads();                               // all conv reads of prods done

    for (int i = tid; i < 4096; i += 512) hist[i] = 0;
    __syncthreads();
    #pragma unroll
    for (int q = 0; q < 4; q++) atomicAdd(&hist[bins[q]], 1u);
    __syncthreads();

    unsigned* gh = hist1 + img * 4096;
    for (int i = tid; i < 4096; i += 512) {
        unsigned v = hist[i];
        if (v) atomicAdd(&gh[i], v);
    }
}

// ---------------- P2: scan hist1 -> coarse bin + count below
__global__ __launch_bounds__(256) void k_scan1(const unsigned* __restrict__ hist1,
                                               int* __restrict__ metaBin,
                                               int* __restrict__ metaBase)
{
    int img = blockIdx.x, tid = threadIdx.x;
    __shared__ unsigned s[256];
    const unsigned* h = hist1 + img * 4096;
    unsigned loc[16], sum = 0;
    #pragma unroll
    for (int j = 0; j < 16; j++) { loc[j] = h[tid * 16 + j]; sum += loc[j]; }
    s[tid] = sum; __syncthreads();
    for (int off = 1; off < 256; off <<= 1) {
        unsigned v = (tid >= off) ? s[tid - off] : 0; __syncthreads();
        s[tid] += v; __syncthreads();
    }
    unsigned incl = s[tid], excl = incl - sum;
    if (K_RANK >= excl && K_RANK < incl) {
        unsigned run = excl;
        #pragma unroll
        for (int j = 0; j < 16; j++) {
            if (K_RANK < run + loc[j]) { metaBin[img] = tid * 16 + j; metaBase[img] = (int)run; break; }
            run += loc[j];
        }
    }
}

// ---------------- P3: refine histogram (low 20 bits) for values in the selected bin
__global__ __launch_bounds__(256) void k_hist2(const float* __restrict__ R,
                                               const int* __restrict__ metaBin,
                                               unsigned* __restrict__ hist2)
{
    int img = blockIdx.x >> 10;                 // 1024 blocks per image
    unsigned b1 = (unsigned)metaBin[img];
    unsigned* h2 = hist2 + ((size_t)img << 20);
    const float4* __restrict__ R4 = (const float4*)R + (size_t)blockIdx.x * 1024;
    #pragma unroll
    for (int j = 0; j < 4; j++) {
        float4 v = R4[threadIdx.x + j * 256];
        unsigned ux = fmap(v.x), uy = fmap(v.y), uz = fmap(v.z), uw = fmap(v.w);
        if ((ux >> 20) == b1) atomicAdd(&h2[ux & 0xFFFFFu], 1u);
        if ((uy >> 20) == b1) atomicAdd(&h2[uy & 0xFFFFFu], 1u);
        if ((uz >> 20) == b1) atomicAdd(&h2[uz & 0xFFFFFu], 1u);
        if ((uw >> 20) == b1) atomicAdd(&h2[uw & 0xFFFFFu], 1u);
    }
}

// ---------------- P4: chunk sums + fused (last-block) exact median locate
__global__ __launch_bounds__(256) void k_med(const unsigned* __restrict__ hist2,
                                             unsigned* __restrict__ chunkSum,
                                             const int* __restrict__ metaBin,
                                             const int* __restrict__ metaBase,
                                             float* __restrict__ med,
                                             unsigned* __restrict__ ticket2)
{
    __shared__ unsigned s[256];
    __shared__ unsigned lastv;
    __shared__ int sel[2];
    const int tid = threadIdx.x;
    const int cb = blockIdx.x, img = blockIdx.y;

    const unsigned* h = hist2 + ((size_t)img << 20) + cb * 4096;
    unsigned sum = 0;
    #pragma unroll
    for (int j = 0; j < 16; j++) sum += h[tid + j * 256];
    s[tid] = sum; __syncthreads();
    for (int off = 128; off > 0; off >>= 1) {
        if (tid < off) s[tid] += s[tid + off];
        __syncthreads();
    }
    if (tid == 0) {
        atomicExch(&chunkSum[img * 256 + cb], s[0]);
        __threadfence();
        lastv = atomicAdd(ticket2, 1u);
    }
    __syncthreads();
    if (lastv != NIMG * 256 - 1) return;

    // final block: locate median for all images
    for (int im = 0; im < NIMG; im++) {
        unsigned target = K_RANK - (unsigned)metaBase[im];
        unsigned v = atomicAdd(&chunkSum[im * 256 + tid], 0u);
        __syncthreads();
        s[tid] = v; __syncthreads();
        for (int off = 1; off < 256; off <<= 1) {
            unsigned t2 = (tid >= off) ? s[tid - off] : 0; __syncthreads();
            s[tid] += t2; __syncthreads();
        }
        unsigned incl = s[tid], excl = incl - v;
        if (target >= excl && target < incl) { sel[0] = tid; sel[1] = (int)excl; }
        __syncthreads();
        int scb = sel[0];
        unsigned cexcl = (unsigned)sel[1];

        const unsigned* hh = hist2 + ((size_t)im << 20) + scb * 4096;
        unsigned loc[16], lsum = 0;
        #pragma unroll
        for (int j = 0; j < 16; j++) { loc[j] = hh[tid * 16 + j]; lsum += loc[j]; }
        __syncthreads();
        s[tid] = lsum; __syncthreads();
        for (int off = 1; off < 256; off <<= 1) {
            unsigned t2 = (tid >= off) ? s[tid - off] : 0; __syncthreads();
            s[tid] += t2; __syncthreads();
        }
        incl = s[tid] + cexcl; excl = s[tid] - lsum + cexcl;
        if (target >= excl && target < incl) {
            unsigned run = excl;
            #pragma unroll
            for (int j = 0; j < 16; j++) {
                if (target < run + loc[j]) {
                    unsigned c = (unsigned)scb * 4096u + (unsigned)tid * 16u + (unsigned)j;
                    unsigned mu = (((unsigned)metaBin[im]) << 20) | c;
                    unsigned fb = (mu & 0x80000000u) ? (mu & 0x7FFFFFFFu) : ~mu;
                    med[im] = __uint_as_float(fb);
                    break;
                }
                run += loc[j];
            }
        }
        __syncthreads();
    }
}

// ---------------- P5: threshold + separable 7x7 max-pool + equality write
__global__ __launch_bounds__(256) void k_out(const float* __restrict__ R,
                                             const float* __restrict__ med,
                                             float* __restrict__ out)
{
    __shared__ float rt[38][39];
    __shared__ float hm[38][33];
    const int tid = threadIdx.x;
    const int img = blockIdx.z;
    const int x0 = blockIdx.x * 32, y0 = blockIdx.y * 32;
    const float m = med[img];
    const float* __restrict__ Ri = R + ((size_t)img << 22);

    for (int i = tid; i < 1444; i += 256) {
        int r = i / 38, c = i - r * 38;
        int gy = y0 - 3 + r, gx = x0 - 3 + c;
        float v = -INFINITY;                      // reduce_window pad = -inf
        if ((unsigned)gy < H && (unsigned)gx < W) {
            float rv = Ri[(size_t)gy * W + gx];
            v = (rv >= m) ? rv : 0.0f;
        }
        rt[r][c] = v;
    }
    __syncthreads();

    for (int i = tid; i < 1216; i += 256) {
        int r = i >> 5, c = i & 31;
        float mx = rt[r][c];
        #pragma unroll
        for (int j = 1; j < 7; j++) mx = fmaxf(mx, rt[r][c + j]);
        hm[r][c] = mx;
    }
    __syncthreads();

    const int txc = tid & 31, ty0 = tid >> 5;
    float* __restrict__ Oi = out + ((size_t)img << 22);
    #pragma unroll
    for (int q = 0; q < 4; q++) {
        int ty = ty0 + q * 8;
        float mx = hm[ty][txc];
        #pragma unroll
        for (int j = 1; j < 7; j++) mx = fmaxf(mx, hm[ty + j][txc]);
        float c = rt[ty + 3][txc + 3];
        Oi[(size_t)(y0 + ty) * W + (x0 + txc)] = (c == mx) ? c : 0.0f;
    }
}

extern "C" void kernel_launch(void* const* d_in, const int* in_sizes, int n_in,
                              void* d_out, int out_size, void* d_ws, size_t ws_size,
                              hipStream_t stream)
{
    const float* x  = (const float*)d_in[0];
    const float* gk = (const float*)d_in[2];        // 7x7 gaussian (49 floats)
    float* out = (float*)d_out;

    char* ws = (char*)d_ws;
    float*    R        = (float*)ws;                                 // 64 MB
    unsigned* hist1    = (unsigned*)(ws + (size_t)HWPX * NIMG * 4);  // 64 KB
    unsigned* ticket1  = hist1 + NIMG * 4096;                        // 4 u32 (unused)
    unsigned* ticket2  = ticket1 + 4;                                // 1 u32
    unsigned* chunkSum = ticket2 + 1;                                // 1024 u32 (fully overwritten)
    int*      metaBin  = (int*)(chunkSum + 1024);                    // 4
    int*      metaBase = metaBin + NIMG;                             // 4
    float*    med      = (float*)(metaBase + NIMG);                  // 4
    double*   kwd      = (double*)(ws + (size_t)HWPX * NIMG * 4 + 71680); // 8B-aligned, past metas
    unsigned* hist2    = (unsigned*)d_out;                           // 16 MB scratch until k_out

    k_prep    <<<32, 512, 0, stream>>>(gk, kwd, hist1);              // also zeros hist1+tickets
    k_harris_R<<<dim3(32, 64, NIMG), 512, 0, stream>>>(x, kwd, R, hist1, hist2); // also zeros hist2
    k_scan1   <<<NIMG, 256, 0, stream>>>(hist1, metaBin, metaBase);
    k_hist2   <<<4096, 256, 0, stream>>>(R, metaBin, hist2);
    k_med     <<<dim3(256, NIMG), 256, 0, stream>>>(hist2, chunkSum, metaBin, metaBase, med, ticket2);
    k_out     <<<dim3(64, 64, NIMG), 256, 0, stream>>>(R, med, out);
}